// Round 6
// baseline (210.809 us; speedup 1.0000x reference)
//
#include <hip/hip_runtime.h>
#include <hip/hip_bf16.h>

typedef _Float16 half4_t  __attribute__((ext_vector_type(4)));
typedef _Float16 half8_t  __attribute__((ext_vector_type(8)));
typedef float    float4_t __attribute__((ext_vector_type(4)));

#define MFMA16x32(a, b, c) __builtin_amdgcn_mfma_f32_16x16x32_f16(a, b, c, 0, 0, 0)

// ---------------------------------------------------------------------------
// Weight cast fp32 -> fp16. Wq 20480 el (20 blocks), Wk 49152 (48), Wv 245760 (240).
// ---------------------------------------------------------------------------
__global__ __launch_bounds__(256)
void wcast_kernel(const float* __restrict__ Wq, const float* __restrict__ Wk,
                  const float* __restrict__ Wv, _Float16* __restrict__ Wqh,
                  _Float16* __restrict__ Wkh, _Float16* __restrict__ Wvh) {
  const int bx = blockIdx.x, tid = threadIdx.x;
  const float* src; _Float16* dst; int idx;
  if (bx < 20)       { src = Wq; dst = Wqh; idx = bx * 256 + tid; }
  else if (bx < 68)  { src = Wk; dst = Wkh; idx = (bx - 20) * 256 + tid; }
  else               { src = Wv; dst = Wvh; idx = (bx - 68) * 256 + tid; }
  float4_t v = *(const float4_t*)(src + (size_t)idx * 4);
  half4_t h = {(_Float16)v[0], (_Float16)v[1], (_Float16)v[2], (_Float16)v[3]};
  *(half4_t*)(dst + (size_t)idx * 4) = h;
}

// ---------------------------------------------------------------------------
// Projections, grid 256 x 512 threads.
// Blocks [0,128): fused KV: OUT[128 x 384] = context[128 x 768] * [Wk;Wv]^T.
//   Context read ONCE for both K and V. K -> natural [row][64]; V -> 16x16x32
//   B-fragment blocks ((b*128+c2b)*20+htg)*512 + lane*8, lane L holding
//   V[h=htg*16+(L&15)][s=c2b*32+8*(L>>4)+j].
// Blocks [128,256): Q: OUT[128 x 64] = tokens[128 x 320] * Wq^T, scale folded.
// k-chunk 32, register-prefetched staging, LDS stride 40 halves (80 B).
// ---------------------------------------------------------------------------
__global__ __launch_bounds__(512, 2)
void proj_kernel(const float* __restrict__ tokens, const float* __restrict__ context,
                 const _Float16* __restrict__ Wqh, const _Float16* __restrict__ Wkh,
                 const _Float16* __restrict__ Wvh, _Float16* __restrict__ Qws,
                 _Float16* __restrict__ Kws, _Float16* __restrict__ Vws) {
  __shared__ alignas(16) _Float16 smem[20480];  // Ach 128*40 | Wch 384*40
  _Float16* Ach = smem;
  _Float16* Wch = smem + 5120;

  const int bx = blockIdx.x, tid = threadIdx.x;
  const int w = tid >> 6, lane = tid & 63;
  const int G = lane >> 4, l15 = lane & 15;

  if (bx < 128) {  // ---------------- fused KV ----------------
    const int m0 = bx * 128;
    const int mg = w >> 2, ng = w & 3;  // waves: 2 m-groups x 4 n-groups

    float4_t acc[4][6];
#pragma unroll
    for (int mi = 0; mi < 4; ++mi)
#pragma unroll
      for (int nt = 0; nt < 6; ++nt) acc[mi][nt] = {0.f, 0.f, 0.f, 0.f};

    float4_t areg[2];
    half8_t wreg[3];
    auto ldA = [&](int kc) {
#pragma unroll
      for (int t = 0; t < 2; ++t) {
        int slot = t * 512 + tid, row = slot >> 3, c4 = slot & 7;
        areg[t] = *(const float4_t*)(context + (size_t)(m0 + row) * 768 + kc * 32 + c4 * 4);
      }
    };
    auto ldW = [&](int kc) {
#pragma unroll
      for (int t = 0; t < 3; ++t) {
        int slot = t * 512 + tid, row = slot >> 2, c8 = slot & 3;
        const _Float16* p = (row < 64) ? (Wkh + (size_t)row * 768)
                                       : (Wvh + (size_t)(row - 64) * 768);
        wreg[t] = *(const half8_t*)(p + kc * 32 + c8 * 8);
      }
    };

    ldA(0); ldW(0);
    for (int kc = 0; kc < 24; ++kc) {
      __syncthreads();
#pragma unroll
      for (int t = 0; t < 2; ++t) {
        int slot = t * 512 + tid, row = slot >> 3, c4 = slot & 7;
        half4_t h = {(_Float16)areg[t][0], (_Float16)areg[t][1],
                     (_Float16)areg[t][2], (_Float16)areg[t][3]};
        *(half4_t*)(Ach + row * 40 + c4 * 4) = h;
      }
#pragma unroll
      for (int t = 0; t < 3; ++t) {
        int slot = t * 512 + tid, row = slot >> 2, c8 = slot & 3;
        *(half8_t*)(Wch + row * 40 + c8 * 8) = wreg[t];
      }
      __syncthreads();
      if (kc + 1 < 24) { ldA(kc + 1); ldW(kc + 1); }
      half8_t af[4], bf[6];
#pragma unroll
      for (int mi = 0; mi < 4; ++mi)
        af[mi] = *(const half8_t*)(Ach + (mg * 64 + mi * 16 + l15) * 40 + 8 * G);
#pragma unroll
      for (int nt = 0; nt < 6; ++nt)
        bf[nt] = *(const half8_t*)(Wch + ((ng * 6 + nt) * 16 + l15) * 40 + 8 * G);
#pragma unroll
      for (int mi = 0; mi < 4; ++mi)
#pragma unroll
        for (int nt = 0; nt < 6; ++nt) acc[mi][nt] = MFMA16x32(af[mi], bf[nt], acc[mi][nt]);
    }

    // K output (n-tiles 0..3, owned by ng==0 waves)
    if (ng == 0) {
#pragma unroll
      for (int mi = 0; mi < 4; ++mi)
#pragma unroll
        for (int nt = 0; nt < 4; ++nt)
#pragma unroll
          for (int r = 0; r < 4; ++r)
            Kws[(size_t)(m0 + mg * 64 + mi * 16 + 4 * G + r) * 64 + nt * 16 + l15] =
                (_Float16)acc[mi][nt][r];
    }
    // V output: bounce through per-wave scratch to fragment-block layout
    __syncthreads();
    _Float16* scr = smem + w * 1152;  // [16 h][72]
    const int b = bx >> 5;
#pragma unroll
    for (int nt = 0; nt < 6; ++nt) {
      int jt = ng * 6 + nt;
      if (jt < 4) continue;
      int htg = jt - 4;
#pragma unroll
      for (int mi = 0; mi < 4; ++mi) {
        half4_t h = {(_Float16)acc[mi][nt][0], (_Float16)acc[mi][nt][1],
                     (_Float16)acc[mi][nt][2], (_Float16)acc[mi][nt][3]};
        *(half4_t*)(scr + l15 * 72 + mi * 16 + 4 * G) = h;
      }
#pragma unroll
      for (int c2 = 0; c2 < 2; ++c2) {
        half8_t fr = *(const half8_t*)(scr + l15 * 72 + c2 * 32 + 8 * G);
        int c2b = (bx & 31) * 4 + mg * 2 + c2;
        *(half8_t*)(Vws + ((size_t)((b * 128 + c2b) * 20 + htg)) * 512 + lane * 8) = fr;
      }
    }
  } else {  // ---------------- Q ----------------
    const int m0 = (bx - 128) * 128;
    const float qsc = 0.125f * 1.44269504088896f;  // 1/sqrt(64) * log2(e)

    float4_t acc[4];
#pragma unroll
    for (int nt = 0; nt < 4; ++nt) acc[nt] = {0.f, 0.f, 0.f, 0.f};

    float4_t areg[2];
    half8_t wreg;
    auto ldA = [&](int kc) {
#pragma unroll
      for (int t = 0; t < 2; ++t) {
        int slot = t * 512 + tid, row = slot >> 3, c4 = slot & 7;
        areg[t] = *(const float4_t*)(tokens + (size_t)(m0 + row) * 320 + kc * 32 + c4 * 4);
      }
    };
    auto ldW = [&](int kc) {
      if (tid < 256) {
        int row = tid >> 2, c8 = tid & 3;
        wreg = *(const half8_t*)(Wqh + (size_t)row * 320 + kc * 32 + c8 * 8);
      }
    };

    ldA(0); ldW(0);
    for (int kc = 0; kc < 10; ++kc) {
      __syncthreads();
#pragma unroll
      for (int t = 0; t < 2; ++t) {
        int slot = t * 512 + tid, row = slot >> 3, c4 = slot & 7;
        half4_t h = {(_Float16)areg[t][0], (_Float16)areg[t][1],
                     (_Float16)areg[t][2], (_Float16)areg[t][3]};
        *(half4_t*)(Ach + row * 40 + c4 * 4) = h;
      }
      if (tid < 256) {
        int row = tid >> 2, c8 = tid & 3;
        *(half8_t*)(Wch + row * 40 + c8 * 8) = wreg;
      }
      __syncthreads();
      if (kc + 1 < 10) { ldA(kc + 1); ldW(kc + 1); }
      half8_t af = *(const half8_t*)(Ach + (w * 16 + l15) * 40 + 8 * G);
#pragma unroll
      for (int nt = 0; nt < 4; ++nt) {
        half8_t bf = *(const half8_t*)(Wch + (nt * 16 + l15) * 40 + 8 * G);
        acc[nt] = MFMA16x32(af, bf, acc[nt]);
      }
    }
#pragma unroll
    for (int nt = 0; nt < 4; ++nt)
#pragma unroll
      for (int r = 0; r < 4; ++r)
        Qws[(size_t)(m0 + w * 16 + 4 * G + r) * 64 + nt * 16 + l15] =
            (_Float16)(acc[nt][r] * qsc);
  }
}

// ---------------------------------------------------------------------------
// Flash cross-attention v3. Grid 512 = 8 XCD-slices x 64 t-blocks; XCD x owns
// (b = x>>1, sh = x&1): K/V working set ~1.6 MB pinned in that XCD's L2.
// 256 threads (4 waves), 2 blocks/CU, barrier-independent overlap.
// Interval = 2 chunks of 32 s, ONE barrier per interval; P and K 4-deep in
// fragment-linear LDS (K staging writes linear tid*16B; P writes XOR-swizzled).
// Every wave: S^T for its (s-tile, t-half) + PV for its 5 h-tiles (80 h).
// V direct global->register, frag-block layout, double-buffered.
// Partial O (fp16) + l (fp32) per s-half; combine kernel finishes.
// ---------------------------------------------------------------------------
__global__ __launch_bounds__(256, 2)
void flash_kernel(const _Float16* __restrict__ Qg, const _Float16* __restrict__ Kg,
                  const _Float16* __restrict__ Vt, _Float16* __restrict__ Op,
                  float* __restrict__ lp) {
  __shared__ alignas(16) _Float16 kbuf[4 * 2048];
  __shared__ alignas(16) _Float16 pbuf[4 * 2048];
  __shared__ float larr[2][4][16];

  const int tid = threadIdx.x, w = tid >> 6, lane = tid & 63;
  const int G = lane >> 4, l15 = lane & 15;
  const int bx = blockIdx.x;
  const int xcd = bx & 7, b = xcd >> 1, sh = xcd & 1;
  const int tblk = (bx >> 3) * 64;
  const int st = w & 1, th = w >> 1;

  // K staging source/dest (linear LDS write: tid*16B)
  const int sB = tid >> 6, sL = tid & 63;
  const int s_loc = (sB >> 1) * 16 + (sL & 15);
  const int e0 = (sB & 1) * 32 + (sL >> 4) * 8;
  const _Float16* kg = Kg + (size_t)(b * 4096 + sh * 2048 + s_loc) * 64 + e0;

  // P swizzle offsets
  const int pidx = (lane ^ ((lane >> 3) & 3)) * 8;   // consumer
  int idxp = (st * 2 + (G >> 1)) * 16 + l15;         // producer
  idxp ^= (idxp >> 3) & 3;
  const int pw = idxp * 8 + 4 * (G & 1);

  // Q B-frags resident
  half8_t qf[2][2];
#pragma unroll
  for (int tt2 = 0; tt2 < 2; ++tt2)
#pragma unroll
    for (int c = 0; c < 2; ++c)
      qf[tt2][c] = *(const half8_t*)(Qg + (size_t)(b * 4096 + tblk + (th * 2 + tt2) * 16 + l15) * 64 + c * 32 + 8 * G);

  float4_t oa[4][5];
#pragma unroll
  for (int tt = 0; tt < 4; ++tt)
#pragma unroll
    for (int ht = 0; ht < 5; ++ht) oa[tt][ht] = {0.f, 0.f, 0.f, 0.f};
  float la[2] = {0.f, 0.f};

  const size_t vbase = (size_t)(b * 128 + sh * 64) * 20;  // frag-block units

  auto kload = [&](int c) { return *(const uint4*)(kg + (size_t)c * 2048); };
  auto kwrite = [&](int buf, uint4 v) { *(uint4*)(&kbuf[buf * 2048 + tid * 8]) = v; };
  auto vload = [&](int c, half8_t v[5]) {
#pragma unroll
    for (int ht = 0; ht < 5; ++ht)
      v[ht] = *(const half8_t*)(Vt + (vbase + (size_t)c * 20 + w * 5 + ht) * 512 + lane * 8);
  };
  auto st_step = [&](int buf) {
    half8_t af0 = *(const half8_t*)(&kbuf[buf * 2048 + (st * 2) * 512 + lane * 8]);
    half8_t af1 = *(const half8_t*)(&kbuf[buf * 2048 + (st * 2 + 1) * 512 + lane * 8]);
#pragma unroll
    for (int tt2 = 0; tt2 < 2; ++tt2) {
      float4_t sa = {0.f, 0.f, 0.f, 0.f};
      sa = MFMA16x32(af0, qf[tt2][0], sa);
      sa = MFMA16x32(af1, qf[tt2][1], sa);
      float ex0 = exp2f(sa[0]), ex1 = exp2f(sa[1]), ex2 = exp2f(sa[2]), ex3 = exp2f(sa[3]);
      la[tt2] += (ex0 + ex1) + (ex2 + ex3);
      half4_t p = {(_Float16)ex0, (_Float16)ex1, (_Float16)ex2, (_Float16)ex3};
      *(half4_t*)(&pbuf[buf * 2048 + (th * 2 + tt2) * 512 + pw]) = p;
    }
  };
  auto pv_step = [&](int buf, const half8_t vv[5]) {
    half8_t pa[4];
#pragma unroll
    for (int tt = 0; tt < 4; ++tt)
      pa[tt] = *(const half8_t*)(&pbuf[buf * 2048 + tt * 512 + pidx]);
#pragma unroll
    for (int ht = 0; ht < 5; ++ht)
#pragma unroll
      for (int tt = 0; tt < 4; ++tt) oa[tt][ht] = MFMA16x32(pa[tt], vv[ht], oa[tt][ht]);
  };

  half8_t vA[5], vB[5], vnA[5], vnB[5];
  uint4 ka, kb;

  // ---- prologue ----
  ka = kload(0); kb = kload(1);
  kwrite(0, ka); kwrite(1, kb);
  ka = kload(2); kb = kload(3);
  __syncthreads();
  st_step(0);
  st_step(1);
  vload(0, vA); vload(1, vB);
  kwrite(2, ka); kwrite(3, kb);
  ka = kload(4); kb = kload(5);
  __syncthreads();

  // ---- main: interval j consumes P(2j),P(2j+1), produces P(2j+2),P(2j+3) ----
#pragma unroll 2
  for (int j = 0; j < 32; ++j) {
    const int c0 = 2 * j, c1 = c0 + 1;
    const int vc0 = (c0 + 2 > 63) ? 63 : c0 + 2;
    const int vc1 = (c1 + 2 > 63) ? 63 : c1 + 2;
    vload(vc0, vnA); vload(vc1, vnB);
    const int kc0 = (c0 + 6 > 63) ? 63 : c0 + 6;
    const int kc1 = (c1 + 6 > 63) ? 63 : c1 + 6;
    uint4 nka = kload(kc0), nkb = kload(kc1);
    if (j < 31) { st_step((c0 + 2) & 3); st_step((c1 + 2) & 3); }
    pv_step(c0 & 3, vA);
    pv_step(c1 & 3, vB);
    kwrite((c0 + 4) & 3, ka); kwrite((c1 + 4) & 3, kb);
    ka = nka; kb = nkb;
#pragma unroll
    for (int ht = 0; ht < 5; ++ht) { vA[ht] = vnA[ht]; vB[ht] = vnB[ht]; }
    __syncthreads();
  }

  // ---- epilogue: partial l + partial O ----
#pragma unroll
  for (int tt2 = 0; tt2 < 2; ++tt2) {
    float v = la[tt2];
    v += __shfl_xor(v, 16);
    v += __shfl_xor(v, 32);
    if (lane < 16) larr[st][th * 2 + tt2][lane] = v;
  }
  __syncthreads();
  if (tid < 64)
    lp[(size_t)sh * 16384 + b * 4096 + tblk + tid] =
        larr[0][tid >> 4][tid & 15] + larr[1][tid >> 4][tid & 15];
  _Float16* myO = Op + (size_t)sh * 5242880;
#pragma unroll
  for (int tt = 0; tt < 4; ++tt)
#pragma unroll
    for (int ht = 0; ht < 5; ++ht)
#pragma unroll
      for (int r = 0; r < 4; ++r)
        myO[(size_t)(b * 4096 + tblk + tt * 16 + 4 * G + r) * 320 + (w * 5 + ht) * 16 + l15] =
            (_Float16)oa[tt][ht][r];
}

// ---------------------------------------------------------------------------
__global__ __launch_bounds__(256)
void combine_kernel(const _Float16* __restrict__ O0, const _Float16* __restrict__ O1,
                    const float* __restrict__ l0, const float* __restrict__ l1,
                    float* __restrict__ out) {
  const int tid = threadIdx.x;
  const int base = blockIdx.x * 1280;  // 16 rows x 80 float4 per block
#pragma unroll
  for (int it = 0; it < 5; ++it) {
    int lin = base + it * 256 + tid;
    int row = lin / 80;
    float inv = 1.0f / (l0[row] + l1[row]);
    half4_t a = *(const half4_t*)(O0 + (size_t)lin * 4);
    half4_t c = *(const half4_t*)(O1 + (size_t)lin * 4);
    float4_t o = {((float)a[0] + (float)c[0]) * inv, ((float)a[1] + (float)c[1]) * inv,
                  ((float)a[2] + (float)c[2]) * inv, ((float)a[3] + (float)c[3]) * inv};
    *(float4_t*)(out + (size_t)lin * 4) = o;
  }
}

// ---------------------------------------------------------------------------
extern "C" void kernel_launch(void* const* d_in, const int* in_sizes, int n_in,
                              void* d_out, int out_size, void* d_ws, size_t ws_size,
                              hipStream_t stream) {
  const float* tokens  = (const float*)d_in[0];  // [4,4096,320]
  const float* context = (const float*)d_in[1];  // [4,4096,768]
  const float* Wq      = (const float*)d_in[2];  // [64,320]
  const float* Wk      = (const float*)d_in[3];  // [64,768]
  const float* Wv      = (const float*)d_in[4];  // [320,768]

  _Float16* Qws = (_Float16*)d_ws;            // 1,048,576 halves
  _Float16* Kws = Qws + (size_t)1048576;      // 1,048,576 halves
  _Float16* Vws = Kws + (size_t)1048576;      // 5,242,880 halves (frag blocks)
  _Float16* O0  = Vws + (size_t)5242880;      // fp16 partials
  _Float16* O1  = O0  + (size_t)5242880;
  float*    l0  = (float*)(O1 + (size_t)5242880);
  float*    l1  = l0 + 16384;
  _Float16* Wqh = (_Float16*)(l1 + 16384);    // 20480 halves
  _Float16* Wkh = Wqh + 20480;                // 49152 halves
  _Float16* Wvh = Wkh + 49152;                // 245760 halves

  wcast_kernel<<<dim3(308), 256, 0, stream>>>(Wq, Wk, Wv, Wqh, Wkh, Wvh);
  proj_kernel<<<dim3(256), 512, 0, stream>>>(tokens, context, Wqh, Wkh, Wvh,
                                             Qws, Kws, Vws);
  flash_kernel<<<dim3(512), 256, 0, stream>>>(Qws, Kws, Vws, O0, l0);
  combine_kernel<<<dim3(1024), 256, 0, stream>>>(O0, O1, l0, l1, (float*)d_out);
}